// Round 14
// baseline (316.072 us; speedup 1.0000x reference)
//
#include <hip/hip_runtime.h>

#define N_NODES 200000
#define N_EDGES 6400000
#define IN_DIM 15
#define POS_DIM 4

#define CSHIFT 8
#define CMASK 255
#define CW 256                                      // nodes per bucket
#define NCOARSE ((N_NODES + CW - 1) >> CSHIFT)      // 782
#define CHUNK 8192                                  // edges per hist/scatter block
#define NBLK ((N_EDGES + CHUNK - 1) / CHUNK)        // 782 (last block 2048 edges)

typedef unsigned uv4 __attribute__((ext_vector_type(4)));

// ---------------- Pass A: per-node precompute ----------------
__global__ void node_prep(const float* __restrict__ x,
                          const float* __restrict__ Wlin,
                          const float* __restrict__ Wsrc,
                          const float* __restrict__ Wdst,
                          const float* __restrict__ Wpos,
                          float2* __restrict__ tabI,
                          float4* __restrict__ tabJ,
                          float2* __restrict__ pvec)
{
    int n = blockIdx.x * blockDim.x + threadIdx.x;
    if (n >= N_NODES) return;
    const float* xp = x + (long)n * IN_DIM;
    float xv[IN_DIM];
#pragma unroll
    for (int k = 0; k < IN_DIM; ++k) xv[k] = xp[k];

    float p0 = 0.f, p1 = 0.f;
#pragma unroll
    for (int k = 0; k < POS_DIM; ++k) {
        p0 += Wpos[k] * xv[k];
        p1 += Wpos[POS_DIM + k] * xv[k];
    }
    float v0 = 0.f, v1 = 0.f, as0 = 0.f, as1 = 0.f, ad0 = 0.f, ad1 = 0.f;
#pragma unroll
    for (int k = 0; k < IN_DIM; ++k) {
        float xk = xv[k];
        v0  += Wlin[k] * xk;           v1  += Wlin[IN_DIM + k] * xk;
        as0 += Wsrc[k] * xk;           as1 += Wsrc[IN_DIM + k] * xk;
        ad0 += Wdst[k] * xk;           ad1 += Wdst[IN_DIM + k] * xk;
    }
    tabI[n] = make_float2(ad0 + p0, ad1 + p1);
    tabJ[n] = make_float4(as0 + p0, as1 + p1, v0 - p0, v1 - p1);
    pvec[n] = make_float2(p0, p1);
}

// ---------------- K1: per-block bucket histogram (512 threads) --------------
__global__ void hist_kernel(const int* __restrict__ idx,
                            unsigned* __restrict__ hist)   // [NBLK][NCOARSE]
{
    __shared__ unsigned h[NCOARSE];
    for (int t = threadIdx.x; t < NCOARSE; t += blockDim.x) h[t] = 0u;
    __syncthreads();
    long s0 = (long)blockIdx.x * CHUNK;
    int end = (int)min((long)CHUNK, (long)N_EDGES - s0);   // always %2048==0
    for (int t = threadIdx.x * 4; t < end; t += 2048) {
        int4 iv = *(const int4*)(idx + s0 + t);
        atomicAdd(&h[iv.x >> CSHIFT], 1u);
        atomicAdd(&h[iv.y >> CSHIFT], 1u);
        atomicAdd(&h[iv.z >> CSHIFT], 1u);
        atomicAdd(&h[iv.w >> CSHIFT], 1u);
    }
    __syncthreads();
    for (int t = threadIdx.x; t < NCOARSE; t += blockDim.x)
        hist[(unsigned)blockIdx.x * NCOARSE + t] = h[t];
}

// ---------------- K2: exclusive scan down each bucket column (782 rows) -----
__global__ void colscan_kernel(unsigned* __restrict__ hist,
                               unsigned* __restrict__ totals)
{
    __shared__ unsigned s[1024];
    int k = blockIdx.x;                      // 782 columns
    int t = threadIdx.x;                     // 512 threads, 2 elems/thread
    int e0 = t, e1 = t + 512;
    unsigned v0 = (e0 < NBLK) ? hist[(unsigned)e0 * NCOARSE + k] : 0u;
    unsigned v1 = (e1 < NBLK) ? hist[(unsigned)e1 * NCOARSE + k] : 0u;
    s[e0] = v0; s[e1] = v1;
    __syncthreads();
    for (int o = 1; o < 1024; o <<= 1) {
        unsigned a0 = (e0 >= o) ? s[e0 - o] : 0u;
        unsigned a1 = (e1 >= o) ? s[e1 - o] : 0u;
        __syncthreads();
        s[e0] += a0; s[e1] += a1;
        __syncthreads();
    }
    if (e0 < NBLK) hist[(unsigned)e0 * NCOARSE + k] = s[e0] - v0;   // exclusive
    if (e1 < NBLK) hist[(unsigned)e1 * NCOARSE + k] = s[e1] - v1;
    if (e1 == NBLK - 1) totals[k] = s[e1];
}

// ---------------- K3: scan of 4-padded totals -> aligned bases (1024 wide) --
__global__ void basescan_kernel(const unsigned* __restrict__ totals,
                                unsigned* __restrict__ base)
{
    __shared__ unsigned s[1024];
    int t = threadIdx.x;                     // blockDim = 512, 2 elems/thread
    int e0 = t, e1 = t + 512;
    unsigned v0 = (e0 < NCOARSE) ? ((totals[e0] + 3u) & ~3u) : 0u;
    unsigned v1 = (e1 < NCOARSE) ? ((totals[e1] + 3u) & ~3u) : 0u;
    s[e0] = v0; s[e1] = v1;
    __syncthreads();
    for (int off = 1; off < 1024; off <<= 1) {
        unsigned a0 = (e0 >= off) ? s[e0 - off] : 0u;
        unsigned a1 = (e1 >= off) ? s[e1 - off] : 0u;
        __syncthreads();
        s[e0] += a0; s[e1] += a1;
        __syncthreads();
    }
    if (e0 < NCOARSE) base[e0] = s[e0] - v0;   // exclusive, multiple of 4
    if (e1 < NCOARSE) base[e1] = s[e1] - v1;
}

// ---------------- K4: LDS-staged scatter (R13-proven, 40 KB LDS) ------------
__global__ void scatter_kernel(const int* __restrict__ idx,
                               const unsigned* __restrict__ hist,
                               const unsigned* __restrict__ base,
                               unsigned* __restrict__ packed)
{
    __shared__ unsigned stage[CHUNK];        // 32 KB
    __shared__ unsigned cnt[1024];           // hist -> exclusive -> inclusive
    __shared__ unsigned gdst[1024];
    int b = blockIdx.x;
    int t = threadIdx.x;                     // 512 threads (8 waves)
    long s0 = (long)b * CHUNK;
    int end = (int)min((long)CHUNK, (long)N_EDGES - s0);   // %2048==0
    cnt[t] = 0u; cnt[t + 512] = 0u;
    __syncthreads();
    // pass 1: local histogram
    for (int e = t * 4; e < end; e += 2048) {
        int4 iv = *(const int4*)(idx + s0 + e);
        atomicAdd(&cnt[iv.x >> CSHIFT], 1u);
        atomicAdd(&cnt[iv.y >> CSHIFT], 1u);
        atomicAdd(&cnt[iv.z >> CSHIFT], 1u);
        atomicAdd(&cnt[iv.w >> CSHIFT], 1u);
    }
    __syncthreads();
    // save own counts, then inclusive scan cnt[] in place (2 elems/thread)
    unsigned c0 = cnt[t], c1 = cnt[t + 512];
    for (int o = 1; o < 1024; o <<= 1) {
        unsigned a0 = (t >= o) ? cnt[t - o] : 0u;
        unsigned a1 = (t + 512 >= o) ? cnt[t + 512 - o] : 0u;
        __syncthreads();
        cnt[t] += a0; cnt[t + 512] += a1;
        __syncthreads();
    }
    unsigned ex0 = cnt[t] - c0;              // exclusive local start
    unsigned ex1 = cnt[t + 512] - c1;
    if (t < NCOARSE) gdst[t] = base[t] + hist[(unsigned)b * NCOARSE + t];
    {
        int u = t + 512;
        if (u < NCOARSE) gdst[u] = base[u] + hist[(unsigned)b * NCOARSE + u];
    }
    __syncthreads();                         // all scan reads done
    cnt[t] = ex0; cnt[t + 512] = ex1;        // cnt becomes cur
    __syncthreads();
    // pass 2: place into LDS stage, bucket-major (restores cnt to inclusive)
    for (int e = t * 4; e < end; e += 2048) {
        int4 iv = *(const int4*)(idx + s0 + e);
        int4 jv = *(const int4*)(idx + N_EDGES + s0 + e);
        unsigned r0 = atomicAdd(&cnt[iv.x >> CSHIFT], 1u);
        unsigned r1 = atomicAdd(&cnt[iv.y >> CSHIFT], 1u);
        unsigned r2 = atomicAdd(&cnt[iv.z >> CSHIFT], 1u);
        unsigned r3 = atomicAdd(&cnt[iv.w >> CSHIFT], 1u);
        stage[r0] = ((unsigned)jv.x << CSHIFT) | (unsigned)(iv.x & CMASK);
        stage[r1] = ((unsigned)jv.y << CSHIFT) | (unsigned)(iv.y & CMASK);
        stage[r2] = ((unsigned)jv.z << CSHIFT) | (unsigned)(iv.z & CMASK);
        stage[r3] = ((unsigned)jv.w << CSHIFT) | (unsigned)(iv.w & CMASK);
    }
    __syncthreads();
    // pass 3: dense copy-out, 16-lane group per bucket run (~10.5 entries)
    int g = t >> 4, l = t & 15;              // 32 groups of 16 lanes
    for (int bk = g; bk < 1024; bk += 32) {
        unsigned st = bk ? cnt[bk - 1] : 0u;   // inclusive[bk-1] == start
        unsigned len = cnt[bk] - st;
        if (len == 0u) continue;
        unsigned gd = gdst[bk];
        for (unsigned e = l; e < len; e += 16u)
            packed[gd + e] = stage[st + e];
    }
}

// ---------------- K5: single-pass LDS-atomic aggregate + finalize -----------
// No sort: stream the bucket window ONCE; per edge gather tabJ[j], read the
// bucket's LDS tabI table, accumulate via 4 LDS f32 atomics into planar
// acc[4][256] (stride-256 -> random-lane ~2-way bank aliasing, free).
// LDS 6 KB (was 41 KB); one stream pass (was two) and no scan barriers.
__global__ void bucket_agg_kernel(const unsigned* __restrict__ packed,
                                  const unsigned* __restrict__ base,
                                  const unsigned* __restrict__ totals,
                                  const float2* __restrict__ tabI,
                                  const float4* __restrict__ tabJ,
                                  const float2* __restrict__ pvec,
                                  const float* __restrict__ bpos,
                                  float2* __restrict__ out)
{
    __shared__ float acc[1024];              // [an0 | an1 | ad0 | ad1] x 256
    __shared__ float2 ti[256];               // tabI + b for this bucket's nodes
    int k = blockIdx.x;
    int t = threadIdx.x;                     // 512 threads
    unsigned s = base[k];
    unsigned n = totals[k];
    float b0 = bpos[0], b1 = bpos[1];
    acc[t] = 0.f; acc[t + 512] = 0.f;
    if (t < 256) {
        int gn = (k << CSHIFT) + t;
        float2 fi = (gn < N_NODES) ? tabI[gn] : make_float2(0.f, 0.f);
        ti[t] = make_float2(fi.x + b0, fi.y + b1);
    }
    __syncthreads();
    // single streaming pass: 4 edges/thread/iter, gathers issued before use
    for (unsigned e = 4u * t; e < n; e += 2048u) {
        uv4 p = __builtin_nontemporal_load((const uv4*)(packed + s + e));
        unsigned pe[4] = {p.x, p.y, p.z, p.w};
        bool ok[4]; int lo[4]; float4 fj[4];
#pragma unroll
        for (int c = 0; c < 4; ++c) {
            ok[c] = (e + (unsigned)c) < n;
            lo[c] = (int)(pe[c] & CMASK);
            int j = ok[c] ? (int)(pe[c] >> CSHIFT) : 0;
            fj[c] = tabJ[j];                 // 4 gathers in flight
        }
#pragma unroll
        for (int c = 0; c < 4; ++c) {
            float2 f = ti[lo[c]];
            float e0 = __expf(f.x - fj[c].x);
            float e1 = __expf(f.y - fj[c].y);
            if (ok[c]) {
                atomicAdd(&acc[lo[c]],       e0 * fj[c].z);
                atomicAdd(&acc[256 + lo[c]], e1 * fj[c].w);
                atomicAdd(&acc[512 + lo[c]], e0);
                atomicAdd(&acc[768 + lo[c]], e1);
            }
        }
    }
    __syncthreads();
    // finalize (t < 256, one node each)
    if (t < 256) {
        int gn = (k << CSHIFT) + t;
        if (gn < N_NODES) {
            float sn0 = acc[t],       sn1 = acc[256 + t];
            float sd0 = acc[512 + t], sd1 = acc[768 + t];
            float2 p = pvec[gn];
            float o0 = (sn0 + (p.x + b0) * sd0) / (sd0 + 1e-16f);
            float o1 = (sn1 + (p.y + b1) * sd1) / (sd1 + 1e-16f);
            out[gn] = make_float2(o0, o1);
        }
    }
}

extern "C" void kernel_launch(void* const* d_in, const int* in_sizes, int n_in,
                              void* d_out, int out_size, void* d_ws, size_t ws_size,
                              hipStream_t stream) {
    const float* x    = (const float*)d_in[0];
    const int*   idx  = (const int*)d_in[1];   // (2, E) flat: [0..E)=i, [E..2E)=j
    const float* Wlin = (const float*)d_in[2];
    const float* Wsrc = (const float*)d_in[3];
    const float* Wdst = (const float*)d_in[4];
    const float* Wpos = (const float*)d_in[5];
    const float* bpos = (const float*)d_in[6];
    float* out = (float*)d_out;

    char* ws = (char*)d_ws;
    size_t off = 0;
    float4* tabJ = (float4*)(ws + off); off += (size_t)N_NODES * 16;
    float2* tabI = (float2*)(ws + off); off += (size_t)N_NODES * 8;
    float2* pvec = (float2*)(ws + off); off += (size_t)N_NODES * 8;
    unsigned* packed = (unsigned*)(ws + off); off += ((size_t)N_EDGES + 4u * NCOARSE) * 4;
    unsigned* hist   = (unsigned*)(ws + off); off += (size_t)NBLK * NCOARSE * 4;
    unsigned* totals = (unsigned*)(ws + off); off += (size_t)NCOARSE * 4;
    unsigned* base   = (unsigned*)(ws + off); off += (size_t)NCOARSE * 4;

    node_prep<<<(N_NODES + 255) / 256, 256, 0, stream>>>(x, Wlin, Wsrc, Wdst, Wpos,
                                                         tabI, tabJ, pvec);
    hist_kernel<<<NBLK, 512, 0, stream>>>(idx, hist);
    colscan_kernel<<<NCOARSE, 512, 0, stream>>>(hist, totals);
    basescan_kernel<<<1, 512, 0, stream>>>(totals, base);
    scatter_kernel<<<NBLK, 512, 0, stream>>>(idx, hist, base, packed);
    bucket_agg_kernel<<<NCOARSE, 512, 0, stream>>>(packed, base, totals,
                                                   tabI, tabJ, pvec, bpos,
                                                   (float2*)out);
}

// Round 15
// 173.312 us; speedup vs baseline: 1.8237x; 1.8237x over previous
//
#include <hip/hip_runtime.h>

#define N_NODES 200000
#define N_EDGES 6400000
#define IN_DIM 15
#define POS_DIM 4

#define CSHIFT 9
#define CMASK 511
#define CW 512                                      // nodes per coarse bucket
#define NCOARSE ((N_NODES + CW - 1) >> CSHIFT)      // 391
#define CHUNK 16384                                 // edges per hist/scatter block
#define NBLK ((N_EDGES + CHUNK - 1) / CHUNK)        // 391
#define CAP 17408                                   // max bucket edges in LDS (+8 sigma)

typedef unsigned uv4 __attribute__((ext_vector_type(4)));

// ---------------- Pass A: per-node precompute ----------------
__global__ void node_prep(const float* __restrict__ x,
                          const float* __restrict__ Wlin,
                          const float* __restrict__ Wsrc,
                          const float* __restrict__ Wdst,
                          const float* __restrict__ Wpos,
                          float2* __restrict__ tabI,
                          float4* __restrict__ tabJ,
                          float2* __restrict__ pvec)
{
    int n = blockIdx.x * blockDim.x + threadIdx.x;
    if (n >= N_NODES) return;
    const float* xp = x + (long)n * IN_DIM;
    float xv[IN_DIM];
#pragma unroll
    for (int k = 0; k < IN_DIM; ++k) xv[k] = xp[k];

    float p0 = 0.f, p1 = 0.f;
#pragma unroll
    for (int k = 0; k < POS_DIM; ++k) {
        p0 += Wpos[k] * xv[k];
        p1 += Wpos[POS_DIM + k] * xv[k];
    }
    float v0 = 0.f, v1 = 0.f, as0 = 0.f, as1 = 0.f, ad0 = 0.f, ad1 = 0.f;
#pragma unroll
    for (int k = 0; k < IN_DIM; ++k) {
        float xk = xv[k];
        v0  += Wlin[k] * xk;           v1  += Wlin[IN_DIM + k] * xk;
        as0 += Wsrc[k] * xk;           as1 += Wsrc[IN_DIM + k] * xk;
        ad0 += Wdst[k] * xk;           ad1 += Wdst[IN_DIM + k] * xk;
    }
    tabI[n] = make_float2(ad0 + p0, ad1 + p1);
    tabJ[n] = make_float4(as0 + p0, as1 + p1, v0 - p0, v1 - p1);
    pvec[n] = make_float2(p0, p1);
}

// ---------------- K1: per-block coarse histogram (512 threads) --------------
__global__ void hist_kernel(const int* __restrict__ idx,
                            unsigned* __restrict__ hist)   // [NBLK][NCOARSE]
{
    __shared__ unsigned h[NCOARSE];
    for (int t = threadIdx.x; t < NCOARSE; t += blockDim.x) h[t] = 0u;
    __syncthreads();
    long s0 = (long)blockIdx.x * CHUNK;
    int end = (int)min((long)CHUNK, (long)N_EDGES - s0);   // always %2048==0
    for (int t = threadIdx.x * 4; t < end; t += 2048) {
        int4 iv = *(const int4*)(idx + s0 + t);
        atomicAdd(&h[iv.x >> CSHIFT], 1u);
        atomicAdd(&h[iv.y >> CSHIFT], 1u);
        atomicAdd(&h[iv.z >> CSHIFT], 1u);
        atomicAdd(&h[iv.w >> CSHIFT], 1u);
    }
    __syncthreads();
    for (int t = threadIdx.x; t < NCOARSE; t += blockDim.x)
        hist[(unsigned)blockIdx.x * NCOARSE + t] = h[t];
}

// ---------------- K2: exclusive scan down each coarse-bucket column ---------
__global__ void colscan_kernel(unsigned* __restrict__ hist,
                               unsigned* __restrict__ totals)
{
    __shared__ unsigned s[512];
    int k = blockIdx.x;
    int t = threadIdx.x;                     // blockDim = 512 >= NBLK
    unsigned v = (t < NBLK) ? hist[(unsigned)t * NCOARSE + k] : 0u;
    s[t] = v;
    __syncthreads();
    for (int off = 1; off < 512; off <<= 1) {
        unsigned add = (t >= off) ? s[t - off] : 0u;
        __syncthreads();
        s[t] += add;
        __syncthreads();
    }
    if (t < NBLK) hist[(unsigned)t * NCOARSE + k] = s[t] - v;   // exclusive
    if (t == NBLK - 1) totals[k] = s[t];
}

// ---------------- K3: scan of 4-padded coarse totals -> aligned bases -------
__global__ void basescan_kernel(const unsigned* __restrict__ totals,
                                unsigned* __restrict__ base)
{
    __shared__ unsigned s[512];
    int t = threadIdx.x;                     // blockDim = 512 >= NCOARSE
    unsigned v = (t < NCOARSE) ? ((totals[t] + 3u) & ~3u) : 0u;
    s[t] = v;
    __syncthreads();
    for (int off = 1; off < 512; off <<= 1) {
        unsigned a = (t >= off) ? s[t - off] : 0u;
        __syncthreads();
        s[t] += a;
        __syncthreads();
    }
    if (t < NCOARSE) base[t] = s[t] - v;     // exclusive, multiple of 4
}

// ---------------- K4: LDS-staged scatter (R11-proven, 512 threads) ----------
// Deterministic block-ordered placement, dense copy-out bursts (~42-entry runs).
__global__ void scatter_kernel(const int* __restrict__ idx,
                               const unsigned* __restrict__ hist,
                               const unsigned* __restrict__ base,
                               unsigned* __restrict__ packed)
{
    __shared__ unsigned stage[CHUNK];        // 64 KB
    __shared__ unsigned cnt[512];            // counts -> cur
    __shared__ unsigned sc[512];             // scan workspace
    __shared__ unsigned lloc[512];           // exclusive local starts
    __shared__ unsigned gdst[NCOARSE];
    int b = blockIdx.x;
    int t = threadIdx.x;                     // 512 threads (8 waves)
    long s0 = (long)b * CHUNK;
    int end = (int)min((long)CHUNK, (long)N_EDGES - s0);   // %2048==0
    cnt[t] = 0u;
    __syncthreads();
    // pass 1: local histogram
    for (int e = t * 4; e < end; e += 2048) {
        int4 iv = *(const int4*)(idx + s0 + e);
        atomicAdd(&cnt[iv.x >> CSHIFT], 1u);
        atomicAdd(&cnt[iv.y >> CSHIFT], 1u);
        atomicAdd(&cnt[iv.z >> CSHIFT], 1u);
        atomicAdd(&cnt[iv.w >> CSHIFT], 1u);
    }
    __syncthreads();
    // inclusive scan over 512 (1 elem/thread)
    sc[t] = cnt[t];
    __syncthreads();
    for (int o = 1; o < 512; o <<= 1) {
        unsigned a = (t >= o) ? sc[t - o] : 0u;
        __syncthreads();
        sc[t] += a;
        __syncthreads();
    }
    {
        unsigned ex = sc[t] - cnt[t];        // exclusive local start
        lloc[t] = ex;
        cnt[t] = ex;                         // cnt becomes cur (own entry only)
        if (t < NCOARSE) gdst[t] = base[t] + hist[(unsigned)b * NCOARSE + t];
    }
    __syncthreads();
    // pass 2: place into LDS stage, bucket-major
    for (int e = t * 4; e < end; e += 2048) {
        int4 iv = *(const int4*)(idx + s0 + e);
        int4 jv = *(const int4*)(idx + N_EDGES + s0 + e);
        unsigned r0 = atomicAdd(&cnt[iv.x >> CSHIFT], 1u);
        unsigned r1 = atomicAdd(&cnt[iv.y >> CSHIFT], 1u);
        unsigned r2 = atomicAdd(&cnt[iv.z >> CSHIFT], 1u);
        unsigned r3 = atomicAdd(&cnt[iv.w >> CSHIFT], 1u);
        stage[r0] = ((unsigned)jv.x << CSHIFT) | (unsigned)(iv.x & CMASK);
        stage[r1] = ((unsigned)jv.y << CSHIFT) | (unsigned)(iv.y & CMASK);
        stage[r2] = ((unsigned)jv.z << CSHIFT) | (unsigned)(iv.z & CMASK);
        stage[r3] = ((unsigned)jv.w << CSHIFT) | (unsigned)(iv.w & CMASK);
    }
    __syncthreads();
    // pass 3: dense copy-out, one wave per bucket run (8 waves)
    int wid = t >> 6, lane = t & 63;
    for (int bk = wid; bk < NCOARSE; bk += 8) {
        unsigned st = lloc[bk];
        unsigned len = ((bk + 1 < 512) ? lloc[bk + 1] : (unsigned)end) - st;
        unsigned gd = gdst[bk];
        for (unsigned e = lane; e < len; e += 64u)
            packed[gd + e] = stage[st + e];
    }
}

// ---------------- K5: fused per-bucket sort + aggregate (R11-proven) --------
// One block per coarse bucket: counting-sort the bucket's L2-hot window into
// LDS (node-major), then 1 node per thread aggregates in registers.
__global__ void bucket_agg_kernel(const unsigned* __restrict__ packed,
                                  const unsigned* __restrict__ base,
                                  const unsigned* __restrict__ totals,
                                  const float2* __restrict__ tabI,
                                  const float4* __restrict__ tabJ,
                                  const float2* __restrict__ pvec,
                                  const float* __restrict__ bpos,
                                  float2* __restrict__ out)
{
    __shared__ unsigned cache[CAP + 512];    // node-major j values (+lane stagger)
    __shared__ unsigned cnt[512], sc[512], cur[512];
    int k = blockIdx.x;
    int t = threadIdx.x;                     // 512 threads, 1 node each
    unsigned s = base[k];
    unsigned n = min(totals[k], (unsigned)CAP);   // loud-fail clamp, never hit
    cnt[t] = 0u;
    __syncthreads();
    // pass 1: histogram of low 9 bits
    for (unsigned e = 4u * t; e < n; e += 2048u) {
        uv4 p = *(const uv4*)(packed + s + e);   // 4-pad -> aligned over-read safe
        atomicAdd(&cnt[p.x & CMASK], 1u);
        if (e + 1 < n) atomicAdd(&cnt[p.y & CMASK], 1u);
        if (e + 2 < n) atomicAdd(&cnt[p.z & CMASK], 1u);
        if (e + 3 < n) atomicAdd(&cnt[p.w & CMASK], 1u);
    }
    __syncthreads();
    // inclusive scan over 512
    sc[t] = cnt[t];
    __syncthreads();
    for (int o = 1; o < 512; o <<= 1) {
        unsigned a = (t >= o) ? sc[t - o] : 0u;
        __syncthreads();
        sc[t] += a;
        __syncthreads();
    }
    unsigned deg = cnt[t];
    unsigned st  = sc[t] - deg + (unsigned)t;   // +lane stagger breaks bank pattern
    cur[t] = st;
    __syncthreads();
    // pass 2: place bare j into LDS, node-major
    for (unsigned e = 4u * t; e < n; e += 2048u) {
        uv4 p = __builtin_nontemporal_load((const uv4*)(packed + s + e));
        { unsigned pos = atomicAdd(&cur[p.x & CMASK], 1u); cache[pos] = p.x >> CSHIFT; }
        if (e + 1 < n) { unsigned pos = atomicAdd(&cur[p.y & CMASK], 1u); cache[pos] = p.y >> CSHIFT; }
        if (e + 2 < n) { unsigned pos = atomicAdd(&cur[p.z & CMASK], 1u); cache[pos] = p.z >> CSHIFT; }
        if (e + 3 < n) { unsigned pos = atomicAdd(&cur[p.w & CMASK], 1u); cache[pos] = p.w >> CSHIFT; }
    }
    __syncthreads();
    // pass 3: per-node register aggregation (1 node per thread)
    float b0 = bpos[0], b1 = bpos[1];
    int gn = (k << CSHIFT) + t;
    if (gn >= N_NODES) return;
    float2 fi = tabI[gn];
    float a0 = fi.x + b0, a1 = fi.y + b1;
    float sn0 = 0.f, sn1 = 0.f, sd0 = 0.f, sd1 = 0.f;
    unsigned e = 0;
    for (; e + 4u <= deg; e += 4u) {
        unsigned j0 = cache[st + e],     j1 = cache[st + e + 1];
        unsigned j2 = cache[st + e + 2], j3 = cache[st + e + 3];
        float4 f0 = tabJ[j0], f1 = tabJ[j1], f2 = tabJ[j2], f3 = tabJ[j3];
        float e00 = __expf(a0 - f0.x), e01 = __expf(a1 - f0.y);
        float e10 = __expf(a0 - f1.x), e11 = __expf(a1 - f1.y);
        float e20 = __expf(a0 - f2.x), e21 = __expf(a1 - f2.y);
        float e30 = __expf(a0 - f3.x), e31 = __expf(a1 - f3.y);
        sn0 += e00 * f0.z + e10 * f1.z + e20 * f2.z + e30 * f3.z;
        sn1 += e01 * f0.w + e11 * f1.w + e21 * f2.w + e31 * f3.w;
        sd0 += e00 + e10 + e20 + e30;
        sd1 += e01 + e11 + e21 + e31;
    }
    for (; e < deg; ++e) {
        unsigned j = cache[st + e];
        float4 fj = tabJ[j];
        float e0 = __expf(a0 - fj.x), e1 = __expf(a1 - fj.y);
        sn0 += e0 * fj.z;  sn1 += e1 * fj.w;
        sd0 += e0;         sd1 += e1;
    }
    float2 p = pvec[gn];
    float o0 = (sn0 + (p.x + b0) * sd0) / (sd0 + 1e-16f);
    float o1 = (sn1 + (p.y + b1) * sd1) / (sd1 + 1e-16f);
    out[gn] = make_float2(o0, o1);
}

extern "C" void kernel_launch(void* const* d_in, const int* in_sizes, int n_in,
                              void* d_out, int out_size, void* d_ws, size_t ws_size,
                              hipStream_t stream) {
    const float* x    = (const float*)d_in[0];
    const int*   idx  = (const int*)d_in[1];   // (2, E) flat: [0..E)=i, [E..2E)=j
    const float* Wlin = (const float*)d_in[2];
    const float* Wsrc = (const float*)d_in[3];
    const float* Wdst = (const float*)d_in[4];
    const float* Wpos = (const float*)d_in[5];
    const float* bpos = (const float*)d_in[6];
    float* out = (float*)d_out;

    char* ws = (char*)d_ws;
    size_t off = 0;
    float4* tabJ = (float4*)(ws + off); off += (size_t)N_NODES * 16;
    float2* tabI = (float2*)(ws + off); off += (size_t)N_NODES * 8;
    float2* pvec = (float2*)(ws + off); off += (size_t)N_NODES * 8;
    unsigned* packed = (unsigned*)(ws + off); off += ((size_t)N_EDGES + 4u * NCOARSE) * 4;
    unsigned* hist   = (unsigned*)(ws + off); off += (size_t)NBLK * NCOARSE * 4;
    unsigned* totals = (unsigned*)(ws + off); off += (size_t)NCOARSE * 4;
    unsigned* base   = (unsigned*)(ws + off); off += (size_t)NCOARSE * 4;

    node_prep<<<(N_NODES + 255) / 256, 256, 0, stream>>>(x, Wlin, Wsrc, Wdst, Wpos,
                                                         tabI, tabJ, pvec);
    hist_kernel<<<NBLK, 512, 0, stream>>>(idx, hist);
    colscan_kernel<<<NCOARSE, 512, 0, stream>>>(hist, totals);
    basescan_kernel<<<1, 512, 0, stream>>>(totals, base);
    scatter_kernel<<<NBLK, 512, 0, stream>>>(idx, hist, base, packed);
    bucket_agg_kernel<<<NCOARSE, 512, 0, stream>>>(packed, base, totals,
                                                   tabI, tabJ, pvec, bpos,
                                                   (float2*)out);
}